// Round 8
// baseline (99.939 us; speedup 1.0000x reference)
//
#include <hip/hip_runtime.h>
#include <hip/hip_bf16.h>
#include <stdint.h>

typedef __attribute__((ext_vector_type(8))) short  s16x8;
typedef __attribute__((ext_vector_type(8))) __bf16 bf16x8;
typedef __attribute__((ext_vector_type(4))) float  f32x4;

#define N_ROWS  32768   // 64 * 512
#define N_CODES 1024
#define DIM     512
#define BK      32      // K-tile (shorts)

static __device__ __forceinline__ short f2bf(float f) {
    unsigned u = __float_as_uint(f);
    u += 0x7fffu + ((u >> 16) & 1u);   // round-to-nearest-even
    return (short)(u >> 16);
}

typedef const __attribute__((address_space(1))) uint32_t guint;
typedef __attribute__((address_space(3))) uint32_t luint;
static __device__ __forceinline__ void gl_lds16(const short* g, short* l) {
    __builtin_amdgcn_global_load_lds((guint*)g, (luint*)l, 16, 0, 0);
}

// ---------------- K0a: convert X to bf16 + row norms ----------------
__global__ void __launch_bounds__(256)
convertX(const float* __restrict__ X, short* __restrict__ Xb,
         float* __restrict__ xnorm) {
    const int lane = threadIdx.x & 63;
    const int row  = blockIdx.x * 4 + (threadIdx.x >> 6);
    const float4* xp = (const float4*)(X + (size_t)row * DIM + lane * 8);
    float4 a = xp[0], b = xp[1];
    s16x8 v = { f2bf(a.x), f2bf(a.y), f2bf(a.z), f2bf(a.w),
                f2bf(b.x), f2bf(b.y), f2bf(b.z), f2bf(b.w) };
    *(s16x8*)(Xb + (size_t)row * DIM + lane * 8) = v;
    float s = a.x*a.x + a.y*a.y + a.z*a.z + a.w*a.w
            + b.x*b.x + b.y*b.y + b.z*b.z + b.w*b.w;
    #pragma unroll
    for (int d = 1; d < 64; d <<= 1) s += __shfl_xor(s, d);
    if (lane == 0) xnorm[row] = s;
}

// ---------------- K0b: convert W to bf16 + codebook norms ----------------
__global__ void __launch_bounds__(256)
convertW(const float* __restrict__ W, short* __restrict__ Wb,
         float* __restrict__ wnorm) {
    const int lane = threadIdx.x & 63;
    const int code = blockIdx.x * 4 + (threadIdx.x >> 6);
    const float4* wp = (const float4*)(W + (size_t)code * DIM + lane * 8);
    float4 a = wp[0], b = wp[1];
    s16x8 v = { f2bf(a.x), f2bf(a.y), f2bf(a.z), f2bf(a.w),
                f2bf(b.x), f2bf(b.y), f2bf(b.z), f2bf(b.w) };
    *(s16x8*)(Wb + (size_t)code * DIM + lane * 8) = v;
    float s = a.x*a.x + a.y*a.y + a.z*a.z + a.w*a.w
            + b.x*b.x + b.y*b.y + b.z*b.z + b.w*b.w;
    #pragma unroll
    for (int d = 1; d < 64; d <<= 1) s += __shfl_xor(s, d);
    if (lane == 0) wnorm[code] = s;
}

// ---------------- K2: bf16 MFMA GEMM (16x16x32) + per-tile argmin ----------------
// 128x128 tile, BK=32. A: double-buffered 2x8KB LDS via global_load_lds with
// the R7-verified 0-conflict layout (16 rows/instr, slot XOR both-sides).
// B: loaded DIRECTLY from global (Wb is L2-resident; per-XCD slice is hot)
// into registers, double-pipelined: t+1's fragments issued one full
// iteration before use. Halves LDS traffic (the R7 serializing resource).
// XCD row-chunk swizzle (FETCH-verified): bid = xcd + 8*colBlk + 64*rowLocal.
__global__ void __launch_bounds__(256)
gemm_argmin(const short* __restrict__ Xb, const short* __restrict__ Wb,
            const float* __restrict__ wnorm, uint32_t* __restrict__ keys) {
    __shared__ __align__(16) short As[2][128 * BK];

    const int tid  = threadIdx.x;
    const int lane = tid & 63;
    const int wave = tid >> 6;
    const int wr = wave >> 1, wc = wave & 1;
    const int lr = lane & 15, kg = lane >> 4;

    const int bid = blockIdx.x;
    const int colBase = ((bid >> 3) & 7) * 128;
    const int rowBase = ((bid & 7) * 32 + (bid >> 6)) * 128;

    // A staging: thread -> rows (tid>>2), (tid>>2)+64, phys slot (tid&3);
    // source k-slot pre-swizzled by (row>>1)&3 = (tid>>3)&3. LDS dest linear.
    const int ssw = ((tid & 3) ^ ((tid >> 3) & 3)) * 8;
    const short* aS = Xb + (size_t)(rowBase + (tid >> 2)) * DIM + ssw;

#define STAGE(buf, t) do {                                                    \
    gl_lds16(aS + (t) * BK,          &As[buf][tid * 8]);                      \
    gl_lds16(aS + 64*DIM + (t) * BK, &As[buf][tid * 8 + 2048]);               \
  } while (0)

    // B fragment pointers: row = colBase + wc*64 + n*16 + lr, 16B at kg*8.
    const short* bP[4];
    #pragma unroll
    for (int n = 0; n < 4; ++n)
        bP[n] = Wb + (size_t)(colBase + wc*64 + n*16 + lr) * DIM + kg * 8;

    f32x4 acc[4][4];
    #pragma unroll
    for (int m = 0; m < 4; ++m)
        #pragma unroll
        for (int n = 0; n < 4; ++n) acc[m][n] = (f32x4)0.f;

    const int fq = (kg ^ ((lr >> 1) & 3)) * 8;   // swizzled read slot (shorts)

    s16x8 bCur[4], bNxt[4];
    #pragma unroll
    for (int n = 0; n < 4; ++n) bCur[n] = *(const s16x8*)(bP[n]);
    STAGE(0, 0);
    __syncthreads();

    for (int t = 0; t < DIM / BK; ++t) {
        const int cur = t & 1;
        if (t < DIM / BK - 1) {
            STAGE(cur ^ 1, t + 1);                       // A prefetch (LDS)
            #pragma unroll
            for (int n = 0; n < 4; ++n)                  // B prefetch (regs)
                bNxt[n] = *(const s16x8*)(bP[n] + (t + 1) * BK);
        }
        bf16x8 aF[4];
        #pragma unroll
        for (int m = 0; m < 4; ++m)
            aF[m] = __builtin_bit_cast(bf16x8,
                *(const s16x8*)&As[cur][(wr*64 + m*16 + lr) * BK + fq]);
        #pragma unroll
        for (int m = 0; m < 4; ++m)
            #pragma unroll
            for (int n = 0; n < 4; ++n)
                acc[m][n] = __builtin_amdgcn_mfma_f32_16x16x32_bf16(
                    aF[m], __builtin_bit_cast(bf16x8, bCur[n]), acc[m][n], 0, 0, 0);
        __syncthreads();   // drains vmcnt -> next As buffer ready
        #pragma unroll
        for (int n = 0; n < 4; ++n) bCur[n] = bNxt[n];
    }
#undef STAGE

    // Epilogue: score = wnorm[col] - 2*dot, packed into sortable u32 with
    // col in the low 10 bits (tie-break = lowest col, like argmin).
    float wn[4]; int wcol[4];
    #pragma unroll
    for (int n = 0; n < 4; ++n) {
        wcol[n] = colBase + wc*64 + n*16 + lr;
        wn[n] = wnorm[wcol[n]];
    }
    const int chunk = (colBase >> 6) + wc;   // 0..15
    #pragma unroll
    for (int m = 0; m < 4; ++m) {
        #pragma unroll
        for (int r = 0; r < 4; ++r) {
            uint32_t best = 0xFFFFFFFFu;
            #pragma unroll
            for (int n = 0; n < 4; ++n) {
                float sc = wn[n] - 2.0f * acc[m][n][r];
                uint32_t u = __float_as_uint(sc);
                u = (u & 0x80000000u) ? ~u : (u | 0x80000000u);  // sortable
                uint32_t key = (u & ~1023u) | (uint32_t)wcol[n];
                best = min(best, key);
            }
            #pragma unroll
            for (int d = 1; d < 16; d <<= 1)
                best = min(best, (uint32_t)__shfl_xor((int)best, d));
            if (lr == 0) {
                const int row = rowBase + wr*64 + m*16 + kg*4 + r;
                keys[(size_t)row * 16 + chunk] = best;
            }
        }
    }
}

// ---------------- K3: min over 16 chunk keys + xnorm -> block partial ----------------
__global__ void __launch_bounds__(256)
reduce_loss(const uint32_t* __restrict__ keys, const float* __restrict__ xnorm,
            float* __restrict__ partial) {
    __shared__ float sm[256];
    const int row = blockIdx.x * 256 + threadIdx.x;
    const uint4* kp = (const uint4*)(keys + (size_t)row * 16);
    uint4 k0 = kp[0], k1 = kp[1], k2 = kp[2], k3 = kp[3];
    uint32_t mk = min(min(min(k0.x, k0.y), min(k0.z, k0.w)),
                      min(min(k1.x, k1.y), min(k1.z, k1.w)));
    mk = min(mk, min(min(min(k2.x, k2.y), min(k2.z, k2.w)),
                     min(min(k3.x, k3.y), min(k3.z, k3.w))));
    // unpack approx score (low 10 bits were col; truncation bias <= 0.0625)
    uint32_t sb = mk & ~1023u;
    float sc = (sb & 0x80000000u) ? __uint_as_float(sb ^ 0x80000000u)
                                  : __uint_as_float(~sb);
    sm[threadIdx.x] = xnorm[row] + sc;   // ||x||^2 + (||w||^2 - 2 x.w)
    __syncthreads();
    for (int st = 128; st > 0; st >>= 1) {
        if (threadIdx.x < st) sm[threadIdx.x] += sm[threadIdx.x + st];
        __syncthreads();
    }
    if (threadIdx.x == 0) partial[blockIdx.x] = sm[0];
}

// ---------------- K4: final mean over 128 partials (double accum) ----------------
__global__ void __launch_bounds__(128)
finalize(const float* __restrict__ partial, float* __restrict__ out) {
    __shared__ double sm[128];
    sm[threadIdx.x] = (double)partial[threadIdx.x];
    __syncthreads();
    for (int st = 64; st > 0; st >>= 1) {
        if (threadIdx.x < st) sm[threadIdx.x] += sm[threadIdx.x + st];
        __syncthreads();
    }
    if (threadIdx.x == 0)
        out[0] = (float)(sm[0] / (double)((size_t)N_ROWS * DIM));
}

extern "C" void kernel_launch(void* const* d_in, const int* in_sizes, int n_in,
                              void* d_out, int out_size, void* d_ws, size_t ws_size,
                              hipStream_t stream) {
    const float* X = (const float*)d_in[0];   // [32768][512]
    const float* W = (const float*)d_in[1];   // [1024][512]
    char* ws = (char*)d_ws;
    short*    Xb      = (short*)ws;                          // 32 MB @ 0
    short*    Wb      = (short*)(ws + 33554432);             // 1 MB
    float*    wnorm   = (float*)(ws + 34603008);             // 4 KB
    float*    xnorm   = (float*)(ws + 34607104);             // 128 KB
    uint32_t* keys    = (uint32_t*)(ws + 34738176);          // 2 MB
    float*    partial = (float*)(ws + 36835328);             // 512 B
    float*    out     = (float*)d_out;

    convertX<<<N_ROWS / 4, 256, 0, stream>>>(X, Xb, xnorm);
    convertW<<<N_CODES / 4, 256, 0, stream>>>(W, Wb, wnorm);
    gemm_argmin<<<2048, 256, 0, stream>>>(Xb, Wb, wnorm, keys);
    reduce_loss<<<N_ROWS / 256, 256, 0, stream>>>(keys, xnorm, partial);
    finalize<<<1, 128, 0, stream>>>(partial, out);
}

// Round 9
// 71.169 us; speedup vs baseline: 1.4042x; 1.4042x over previous
//
#include <hip/hip_runtime.h>
#include <hip/hip_bf16.h>
#include <stdint.h>

typedef __attribute__((ext_vector_type(8))) short  s16x8;
typedef __attribute__((ext_vector_type(8))) __bf16 bf16x8;
typedef __attribute__((ext_vector_type(4))) float  f32x4;

#define N_ROWS  32768   // 64 * 512
#define N_CODES 1024
#define DIM     512
#define BK      32      // K-tile (shorts)
#define NT      (DIM / BK)   // 16 K-steps

static __device__ __forceinline__ short f2bf(float f) {
    unsigned u = __float_as_uint(f);
    u += 0x7fffu + ((u >> 16) & 1u);   // round-to-nearest-even
    return (short)(u >> 16);
}

typedef const __attribute__((address_space(1))) uint32_t guint;
typedef __attribute__((address_space(3))) uint32_t luint;
static __device__ __forceinline__ void gl_lds16(const short* g, short* l) {
    __builtin_amdgcn_global_load_lds((guint*)g, (luint*)l, 16, 0, 0);
}

// ---------------- K0a: convert X to bf16 + row norms ----------------
__global__ void __launch_bounds__(256)
convertX(const float* __restrict__ X, short* __restrict__ Xb,
         float* __restrict__ xnorm) {
    const int lane = threadIdx.x & 63;
    const int row  = blockIdx.x * 4 + (threadIdx.x >> 6);
    const float4* xp = (const float4*)(X + (size_t)row * DIM + lane * 8);
    float4 a = xp[0], b = xp[1];
    s16x8 v = { f2bf(a.x), f2bf(a.y), f2bf(a.z), f2bf(a.w),
                f2bf(b.x), f2bf(b.y), f2bf(b.z), f2bf(b.w) };
    *(s16x8*)(Xb + (size_t)row * DIM + lane * 8) = v;
    float s = a.x*a.x + a.y*a.y + a.z*a.z + a.w*a.w
            + b.x*b.x + b.y*b.y + b.z*b.z + b.w*b.w;
    #pragma unroll
    for (int d = 1; d < 64; d <<= 1) s += __shfl_xor(s, d);
    if (lane == 0) xnorm[row] = s;
}

// ---------------- K0b: convert W to bf16 + codebook norms ----------------
__global__ void __launch_bounds__(256)
convertW(const float* __restrict__ W, short* __restrict__ Wb,
         float* __restrict__ wnorm) {
    const int lane = threadIdx.x & 63;
    const int code = blockIdx.x * 4 + (threadIdx.x >> 6);
    const float4* wp = (const float4*)(W + (size_t)code * DIM + lane * 8);
    float4 a = wp[0], b = wp[1];
    s16x8 v = { f2bf(a.x), f2bf(a.y), f2bf(a.z), f2bf(a.w),
                f2bf(b.x), f2bf(b.y), f2bf(b.z), f2bf(b.w) };
    *(s16x8*)(Wb + (size_t)code * DIM + lane * 8) = v;
    float s = a.x*a.x + a.y*a.y + a.z*a.z + a.w*a.w
            + b.x*b.x + b.y*b.y + b.z*b.z + b.w*b.w;
    #pragma unroll
    for (int d = 1; d < 64; d <<= 1) s += __shfl_xor(s, d);
    if (lane == 0) wnorm[code] = s;
}

// ---------------- K2: bf16 MFMA GEMM (16x16x32) + per-tile argmin ----------------
// R7 base (55us, 0 bank conflicts) + counted-vmcnt deep pipeline (T3/T4):
// TRIPLE-buffered LDS (3x16KB), prefetch depth 2, raw s_barrier with
// s_waitcnt vmcnt(4) gate (never 0 until tail) -> each stage gets ~2
// iterations of latency cover instead of <1. Loop fully unrolled so the
// vmcnt immediates and %3 buffer indices are compile-time.
// A+B both staged via global_load_lds (R8 proved per-lane B gathers are a
// 4x L2-sector-amplified disaster). 0-conflict layout: 16 rows/instr,
// slot XOR phys = kg ^ ((row>>1)&3), both-sides.
// XCD row-chunk swizzle (FETCH-verified): bid = xcd + 8*colBlk + 64*rowLocal.
__global__ void __launch_bounds__(256)
gemm_argmin(const short* __restrict__ Xb, const short* __restrict__ Wb,
            const float* __restrict__ wnorm, uint32_t* __restrict__ keys) {
    __shared__ __align__(16) short As[3][128 * BK];
    __shared__ __align__(16) short Bs[3][128 * BK];

    const int tid  = threadIdx.x;
    const int lane = tid & 63;
    const int wave = tid >> 6;
    const int wr = wave >> 1, wc = wave & 1;
    const int lr = lane & 15, kg = lane >> 4;

    const int bid = blockIdx.x;
    const int colBase = ((bid >> 3) & 7) * 128;
    const int rowBase = ((bid & 7) * 32 + (bid >> 6)) * 128;

    // staging: thread -> rows (tid>>2) and (tid>>2)+64, phys slot (tid&3);
    // source k-slot pre-swizzled by (row>>1)&3 = (tid>>3)&3. LDS dest linear.
    const int ssw = ((tid & 3) ^ ((tid >> 3) & 3)) * 8;
    const short* aS = Xb + (size_t)(rowBase + (tid >> 2)) * DIM + ssw;
    const short* bS = Wb + (size_t)(colBase + (tid >> 2)) * DIM + ssw;

#define STAGE(buf, t) do {                                                    \
    gl_lds16(aS + (t) * BK,            &As[buf][tid * 8]);                    \
    gl_lds16(aS + 64*DIM + (t) * BK,   &As[buf][tid * 8 + 2048]);             \
    gl_lds16(bS + (t) * BK,            &Bs[buf][tid * 8]);                    \
    gl_lds16(bS + 64*DIM + (t) * BK,   &Bs[buf][tid * 8 + 2048]);             \
  } while (0)

    f32x4 acc[4][4];
    #pragma unroll
    for (int m = 0; m < 4; ++m)
        #pragma unroll
        for (int n = 0; n < 4; ++n) acc[m][n] = (f32x4)0.f;

    const int fq = (kg ^ ((lr >> 1) & 3)) * 8;   // swizzled read slot (shorts)

    // prologue: 2-deep prefetch; wait only for tile 0 (4 newest stay in flight)
    STAGE(0, 0);
    STAGE(1, 1);
    asm volatile("s_waitcnt vmcnt(4)" ::: "memory");
    __builtin_amdgcn_s_barrier();

    #pragma unroll
    for (int t = 0; t < NT; ++t) {
        const int cur = t % 3;
        if (t + 2 < NT) STAGE((t + 2) % 3, t + 2);   // depth-2 prefetch
        bf16x8 aF[4], bF[4];
        #pragma unroll
        for (int m = 0; m < 4; ++m)
            aF[m] = __builtin_bit_cast(bf16x8,
                *(const s16x8*)&As[cur][(wr*64 + m*16 + lr) * BK + fq]);
        #pragma unroll
        for (int n = 0; n < 4; ++n)
            bF[n] = __builtin_bit_cast(bf16x8,
                *(const s16x8*)&Bs[cur][(wc*64 + n*16 + lr) * BK + fq]);
        #pragma unroll
        for (int m = 0; m < 4; ++m)
            #pragma unroll
            for (int n = 0; n < 4; ++n)
                acc[m][n] = __builtin_amdgcn_mfma_f32_16x16x32_bf16(
                    aF[m], bF[n], acc[m][n], 0, 0, 0);
        // gate: stage(t+1) must be landed before next iter reads it;
        // stage(t+2)'s 4 loads stay in flight (counted, never 0 until tail).
        if (t < NT - 2) {
            asm volatile("s_waitcnt vmcnt(4)" ::: "memory");
            __builtin_amdgcn_s_barrier();
        } else if (t == NT - 2) {
            asm volatile("s_waitcnt vmcnt(0)" ::: "memory");
            __builtin_amdgcn_s_barrier();
        }
    }
#undef STAGE

    // Epilogue: score = wnorm[col] - 2*dot, packed into sortable u32 with
    // col in the low 10 bits (tie-break = lowest col, like argmin).
    float wn[4]; int wcol[4];
    #pragma unroll
    for (int n = 0; n < 4; ++n) {
        wcol[n] = colBase + wc*64 + n*16 + lr;
        wn[n] = wnorm[wcol[n]];
    }
    const int chunk = (colBase >> 6) + wc;   // 0..15
    #pragma unroll
    for (int m = 0; m < 4; ++m) {
        #pragma unroll
        for (int r = 0; r < 4; ++r) {
            uint32_t best = 0xFFFFFFFFu;
            #pragma unroll
            for (int n = 0; n < 4; ++n) {
                float sc = wn[n] - 2.0f * acc[m][n][r];
                uint32_t u = __float_as_uint(sc);
                u = (u & 0x80000000u) ? ~u : (u | 0x80000000u);  // sortable
                uint32_t key = (u & ~1023u) | (uint32_t)wcol[n];
                best = min(best, key);
            }
            #pragma unroll
            for (int d = 1; d < 16; d <<= 1)
                best = min(best, (uint32_t)__shfl_xor((int)best, d));
            if (lr == 0) {
                const int row = rowBase + wr*64 + m*16 + kg*4 + r;
                keys[(size_t)row * 16 + chunk] = best;
            }
        }
    }
}

// ---------------- K3: min over 16 chunk keys + xnorm -> block partial ----------------
__global__ void __launch_bounds__(256)
reduce_loss(const uint32_t* __restrict__ keys, const float* __restrict__ xnorm,
            float* __restrict__ partial) {
    __shared__ float sm[256];
    const int row = blockIdx.x * 256 + threadIdx.x;
    const uint4* kp = (const uint4*)(keys + (size_t)row * 16);
    uint4 k0 = kp[0], k1 = kp[1], k2 = kp[2], k3 = kp[3];
    uint32_t mk = min(min(min(k0.x, k0.y), min(k0.z, k0.w)),
                      min(min(k1.x, k1.y), min(k1.z, k1.w)));
    mk = min(mk, min(min(min(k2.x, k2.y), min(k2.z, k2.w)),
                     min(min(k3.x, k3.y), min(k3.z, k3.w))));
    // unpack approx score (low 10 bits were col; truncation bias <= 0.0625)
    uint32_t sb = mk & ~1023u;
    float sc = (sb & 0x80000000u) ? __uint_as_float(sb ^ 0x80000000u)
                                  : __uint_as_float(~sb);
    sm[threadIdx.x] = xnorm[row] + sc;   // ||x||^2 + (||w||^2 - 2 x.w)
    __syncthreads();
    for (int st = 128; st > 0; st >>= 1) {
        if (threadIdx.x < st) sm[threadIdx.x] += sm[threadIdx.x + st];
        __syncthreads();
    }
    if (threadIdx.x == 0) partial[blockIdx.x] = sm[0];
}

// ---------------- K4: final mean over 128 partials (double accum) ----------------
__global__ void __launch_bounds__(128)
finalize(const float* __restrict__ partial, float* __restrict__ out) {
    __shared__ double sm[128];
    sm[threadIdx.x] = (double)partial[threadIdx.x];
    __syncthreads();
    for (int st = 64; st > 0; st >>= 1) {
        if (threadIdx.x < st) sm[threadIdx.x] += sm[threadIdx.x + st];
        __syncthreads();
    }
    if (threadIdx.x == 0)
        out[0] = (float)(sm[0] / (double)((size_t)N_ROWS * DIM));
}

extern "C" void kernel_launch(void* const* d_in, const int* in_sizes, int n_in,
                              void* d_out, int out_size, void* d_ws, size_t ws_size,
                              hipStream_t stream) {
    const float* X = (const float*)d_in[0];   // [32768][512]
    const float* W = (const float*)d_in[1];   // [1024][512]
    char* ws = (char*)d_ws;
    short*    Xb      = (short*)ws;                          // 32 MB @ 0
    short*    Wb      = (short*)(ws + 33554432);             // 1 MB
    float*    wnorm   = (float*)(ws + 34603008);             // 4 KB
    float*    xnorm   = (float*)(ws + 34607104);             // 128 KB
    uint32_t* keys    = (uint32_t*)(ws + 34738176);          // 2 MB
    float*    partial = (float*)(ws + 36835328);             // 512 B
    float*    out     = (float*)d_out;

    convertX<<<N_ROWS / 4, 256, 0, stream>>>(X, Xb, xnorm);
    convertW<<<N_CODES / 4, 256, 0, stream>>>(W, Wb, wnorm);
    gemm_argmin<<<2048, 256, 0, stream>>>(Xb, Wb, wnorm, keys);
    reduce_loss<<<N_ROWS / 256, 256, 0, stream>>>(keys, xnorm, partial);
    finalize<<<1, 128, 0, stream>>>(partial, out);
}

// Round 10
// 70.358 us; speedup vs baseline: 1.4204x; 1.0115x over previous
//
#include <hip/hip_runtime.h>
#include <hip/hip_bf16.h>
#include <stdint.h>

typedef __attribute__((ext_vector_type(8))) short  s16x8;
typedef __attribute__((ext_vector_type(8))) __bf16 bf16x8;
typedef __attribute__((ext_vector_type(4))) float  f32x4;

#define N_ROWS  32768   // 64 * 512
#define N_CODES 1024
#define DIM     512
#define BK      32      // K-tile (shorts)
#define NT      (DIM / BK)   // 16 K-steps

static __device__ __forceinline__ short f2bf(float f) {
    unsigned u = __float_as_uint(f);
    u += 0x7fffu + ((u >> 16) & 1u);   // round-to-nearest-even
    return (short)(u >> 16);
}

typedef const __attribute__((address_space(1))) uint32_t guint;
typedef __attribute__((address_space(3))) uint32_t luint;
static __device__ __forceinline__ void gl_lds16(const short* g, short* l) {
    __builtin_amdgcn_global_load_lds((guint*)g, (luint*)l, 16, 0, 0);
}

// ---------------- K0a: convert X to bf16 + row norms ----------------
__global__ void __launch_bounds__(256)
convertX(const float* __restrict__ X, short* __restrict__ Xb,
         float* __restrict__ xnorm) {
    const int lane = threadIdx.x & 63;
    const int row  = blockIdx.x * 4 + (threadIdx.x >> 6);
    const float4* xp = (const float4*)(X + (size_t)row * DIM + lane * 8);
    float4 a = xp[0], b = xp[1];
    s16x8 v = { f2bf(a.x), f2bf(a.y), f2bf(a.z), f2bf(a.w),
                f2bf(b.x), f2bf(b.y), f2bf(b.z), f2bf(b.w) };
    *(s16x8*)(Xb + (size_t)row * DIM + lane * 8) = v;
    float s = a.x*a.x + a.y*a.y + a.z*a.z + a.w*a.w
            + b.x*b.x + b.y*b.y + b.z*b.z + b.w*b.w;
    #pragma unroll
    for (int d = 1; d < 64; d <<= 1) s += __shfl_xor(s, d);
    if (lane == 0) xnorm[row] = s;
}

// ---------------- K0b: convert W to bf16 + codebook norms ----------------
__global__ void __launch_bounds__(256)
convertW(const float* __restrict__ W, short* __restrict__ Wb,
         float* __restrict__ wnorm) {
    const int lane = threadIdx.x & 63;
    const int code = blockIdx.x * 4 + (threadIdx.x >> 6);
    const float4* wp = (const float4*)(W + (size_t)code * DIM + lane * 8);
    float4 a = wp[0], b = wp[1];
    s16x8 v = { f2bf(a.x), f2bf(a.y), f2bf(a.z), f2bf(a.w),
                f2bf(b.x), f2bf(b.y), f2bf(b.z), f2bf(b.w) };
    *(s16x8*)(Wb + (size_t)code * DIM + lane * 8) = v;
    float s = a.x*a.x + a.y*a.y + a.z*a.z + a.w*a.w
            + b.x*b.x + b.y*b.y + b.z*b.z + b.w*b.w;
    #pragma unroll
    for (int d = 1; d < 64; d <<= 1) s += __shfl_xor(s, d);
    if (lane == 0) wnorm[code] = s;
}

// ---------------- K2: bf16 MFMA GEMM (16x16x32) + per-tile argmin ----------------
// R9 diagnosis: LDS data pipe is the serializing resource (ds_read bytes/FLOP).
// Fix: wave tile 64x128 -> 32 MFMA per 12 ds_reads (was 16/8), block 128x256.
// Carries over every verified piece: 0-conflict read form (16 rows/instr,
// slot XOR both-sides), global_load_lds staging (linear dest, pre-swizzled
// source), triple-buffer + counted vmcnt(6) gate, XCD row-chunk swizzle
// (per-XCD 4096-row Xb slice = 4MB L2-resident), packed-key argmin epilogue.
__global__ void __launch_bounds__(256, 2)
gemm_argmin(const short* __restrict__ Xb, const short* __restrict__ Wb,
            const float* __restrict__ wnorm, uint32_t* __restrict__ keys) {
    __shared__ __align__(16) short As[3][128 * BK];   // 24 KB
    __shared__ __align__(16) short Bs[3][256 * BK];   // 48 KB

    const int tid  = threadIdx.x;
    const int lane = tid & 63;
    const int wave = tid >> 6;
    const int wr = wave >> 1, wc = wave & 1;
    const int lr = lane & 15, kg = lane >> 4;

    // bid = xcd + 8*colBlk(0..3) + 32*rowLocal(0..31); grid 1024.
    const int bid = blockIdx.x;
    const int colBase = ((bid >> 3) & 3) * 256;
    const int rowBase = ((bid & 7) * 32 + (bid >> 5)) * 128;

    // staging: thread -> row (tid>>2) (+64/+128/+192), phys slot (tid&3);
    // source k-slot pre-swizzled by (row>>1)&3 = (tid>>3)&3 (row deltas of 64
    // leave (row>>1)&3 unchanged). LDS dest linear.
    const int ssw = ((tid & 3) ^ ((tid >> 3) & 3)) * 8;
    const short* aS = Xb + (size_t)(rowBase + (tid >> 2)) * DIM + ssw;
    const short* bS = Wb + (size_t)(colBase + (tid >> 2)) * DIM + ssw;

#define STAGE(buf, t) do {                                                    \
    gl_lds16(aS + (t) * BK,            &As[buf][tid * 8]);                    \
    gl_lds16(aS + 64*DIM + (t) * BK,   &As[buf][tid * 8 + 2048]);             \
    gl_lds16(bS + (t) * BK,            &Bs[buf][tid * 8]);                    \
    gl_lds16(bS + 64*DIM + (t) * BK,   &Bs[buf][tid * 8 + 2048]);             \
    gl_lds16(bS + 128*DIM + (t) * BK,  &Bs[buf][tid * 8 + 4096]);             \
    gl_lds16(bS + 192*DIM + (t) * BK,  &Bs[buf][tid * 8 + 6144]);             \
  } while (0)

    f32x4 acc[4][8];
    #pragma unroll
    for (int m = 0; m < 4; ++m)
        #pragma unroll
        for (int n = 0; n < 8; ++n) acc[m][n] = (f32x4)0.f;

    const int fq = (kg ^ ((lr >> 1) & 3)) * 8;   // swizzled read slot (shorts)

    // prologue: 2-deep prefetch; retire tile 0's 6 loads only.
    STAGE(0, 0);
    STAGE(1, 1);
    asm volatile("s_waitcnt vmcnt(6)" ::: "memory");
    __builtin_amdgcn_s_barrier();

    #pragma unroll
    for (int t = 0; t < NT; ++t) {
        const int cur = t % 3;
        if (t + 2 < NT) STAGE((t + 2) % 3, t + 2);   // depth-2 prefetch
        bf16x8 aF[4], bF[8];
        #pragma unroll
        for (int m = 0; m < 4; ++m)
            aF[m] = __builtin_bit_cast(bf16x8,
                *(const s16x8*)&As[cur][(wr*64 + m*16 + lr) * BK + fq]);
        #pragma unroll
        for (int n = 0; n < 8; ++n)
            bF[n] = __builtin_bit_cast(bf16x8,
                *(const s16x8*)&Bs[cur][(wc*128 + n*16 + lr) * BK + fq]);
        #pragma unroll
        for (int m = 0; m < 4; ++m)
            #pragma unroll
            for (int n = 0; n < 8; ++n)
                acc[m][n] = __builtin_amdgcn_mfma_f32_16x16x32_bf16(
                    aF[m], bF[n], acc[m][n], 0, 0, 0);
        // gate: stage(t+1) landed; stage(t+2)'s 6 loads stay in flight.
        if (t < NT - 2) {
            asm volatile("s_waitcnt vmcnt(6)" ::: "memory");
            __builtin_amdgcn_s_barrier();
        } else if (t == NT - 2) {
            asm volatile("s_waitcnt vmcnt(0)" ::: "memory");
            __builtin_amdgcn_s_barrier();
        }
    }
#undef STAGE

    // Epilogue: score = wnorm[col] - 2*dot, packed sortable u32 (col in low
    // 10 bits, tie-break = lowest col). 2 chunk-groups of 4 n-frags each.
    float wn[8]; int wcol[8];
    #pragma unroll
    for (int n = 0; n < 8; ++n) {
        wcol[n] = colBase + wc*128 + n*16 + lr;
        wn[n] = wnorm[wcol[n]];
    }
    #pragma unroll
    for (int m = 0; m < 4; ++m) {
        #pragma unroll
        for (int r = 0; r < 4; ++r) {
            #pragma unroll
            for (int g = 0; g < 2; ++g) {
                uint32_t best = 0xFFFFFFFFu;
                #pragma unroll
                for (int j = 0; j < 4; ++j) {
                    const int n = g * 4 + j;
                    float sc = wn[n] - 2.0f * acc[m][n][r];
                    uint32_t u = __float_as_uint(sc);
                    u = (u & 0x80000000u) ? ~u : (u | 0x80000000u);  // sortable
                    uint32_t key = (u & ~1023u) | (uint32_t)wcol[n];
                    best = min(best, key);
                }
                #pragma unroll
                for (int d = 1; d < 16; d <<= 1)
                    best = min(best, (uint32_t)__shfl_xor((int)best, d));
                if (lr == 0) {
                    const int row = rowBase + wr*64 + m*16 + kg*4 + r;
                    keys[(size_t)row * 16 + (colBase >> 6) + wc*2 + g] = best;
                }
            }
        }
    }
}

// ---------------- K3: min over 16 chunk keys + xnorm -> block partial ----------------
__global__ void __launch_bounds__(256)
reduce_loss(const uint32_t* __restrict__ keys, const float* __restrict__ xnorm,
            float* __restrict__ partial) {
    __shared__ float sm[256];
    const int row = blockIdx.x * 256 + threadIdx.x;
    const uint4* kp = (const uint4*)(keys + (size_t)row * 16);
    uint4 k0 = kp[0], k1 = kp[1], k2 = kp[2], k3 = kp[3];
    uint32_t mk = min(min(min(k0.x, k0.y), min(k0.z, k0.w)),
                      min(min(k1.x, k1.y), min(k1.z, k1.w)));
    mk = min(mk, min(min(min(k2.x, k2.y), min(k2.z, k2.w)),
                     min(min(k3.x, k3.y), min(k3.z, k3.w))));
    // unpack approx score (low 10 bits were col; truncation bias <= 0.0625)
    uint32_t sb = mk & ~1023u;
    float sc = (sb & 0x80000000u) ? __uint_as_float(sb ^ 0x80000000u)
                                  : __uint_as_float(~sb);
    sm[threadIdx.x] = xnorm[row] + sc;   // ||x||^2 + (||w||^2 - 2 x.w)
    __syncthreads();
    for (int st = 128; st > 0; st >>= 1) {
        if (threadIdx.x < st) sm[threadIdx.x] += sm[threadIdx.x + st];
        __syncthreads();
    }
    if (threadIdx.x == 0) partial[blockIdx.x] = sm[0];
}

// ---------------- K4: final mean over 128 partials (double accum) ----------------
__global__ void __launch_bounds__(128)
finalize(const float* __restrict__ partial, float* __restrict__ out) {
    __shared__ double sm[128];
    sm[threadIdx.x] = (double)partial[threadIdx.x];
    __syncthreads();
    for (int st = 64; st > 0; st >>= 1) {
        if (threadIdx.x < st) sm[threadIdx.x] += sm[threadIdx.x + st];
        __syncthreads();
    }
    if (threadIdx.x == 0)
        out[0] = (float)(sm[0] / (double)((size_t)N_ROWS * DIM));
}

extern "C" void kernel_launch(void* const* d_in, const int* in_sizes, int n_in,
                              void* d_out, int out_size, void* d_ws, size_t ws_size,
                              hipStream_t stream) {
    const float* X = (const float*)d_in[0];   // [32768][512]
    const float* W = (const float*)d_in[1];   // [1024][512]
    char* ws = (char*)d_ws;
    short*    Xb      = (short*)ws;                          // 32 MB @ 0
    short*    Wb      = (short*)(ws + 33554432);             // 1 MB
    float*    wnorm   = (float*)(ws + 34603008);             // 4 KB
    float*    xnorm   = (float*)(ws + 34607104);             // 128 KB
    uint32_t* keys    = (uint32_t*)(ws + 34738176);          // 2 MB
    float*    partial = (float*)(ws + 36835328);             // 512 B
    float*    out     = (float*)d_out;

    convertX<<<N_ROWS / 4, 256, 0, stream>>>(X, Xb, xnorm);
    convertW<<<N_CODES / 4, 256, 0, stream>>>(W, Wb, wnorm);
    gemm_argmin<<<1024, 256, 0, stream>>>(Xb, Wb, wnorm, keys);
    reduce_loss<<<N_ROWS / 256, 256, 0, stream>>>(keys, xnorm, partial);
    finalize<<<1, 128, 0, stream>>>(partial, out);
}